// Round 3
// baseline (294.783 us; speedup 1.0000x reference)
//
#include <hip/hip_runtime.h>
#include <hip/hip_bf16.h>
#include <stdint.h>

#define BATCH 4
#define SEQ   4096          // 64*64 spatial
#define CH    512
#define NGRP  32
#define GEPS  1e-6f

typedef short  short8  __attribute__((ext_vector_type(8)));
typedef float  floatx4 __attribute__((ext_vector_type(4)));
typedef long   longx2  __attribute__((ext_vector_type(2)));

static __device__ __forceinline__ short bf16b(float f) {
    __hip_bfloat16 h = __float2bfloat16(f);
    return __builtin_bit_cast(short, h);
}
static __device__ __forceinline__ float bf2f(short s) {
    unsigned u = ((unsigned)(unsigned short)s) << 16;
    return __builtin_bit_cast(float, u);
}
static __device__ __forceinline__ char fp8b(float f) {
    int pk = __builtin_amdgcn_cvt_pk_fp8_f32(f, f, 0, false);
    return (char)(pk & 0xff);
}

// async global->LDS, 16B per lane. LDS dest = wave-uniform base + lane*16.
static __device__ __forceinline__ void dma16(const void* g, void* l) {
    __builtin_amdgcn_global_load_lds(
        (const __attribute__((address_space(1))) unsigned int*)g,
        (__attribute__((address_space(3))) unsigned int*)l, 16, 0, 0);
}

// max-reduce across the 16 lanes of a DPP row, pure VALU
static __device__ __forceinline__ float rowmax16(float x) {
    int xi = __builtin_bit_cast(int, x);
    x = fmaxf(x, __builtin_bit_cast(float, __builtin_amdgcn_update_dpp(xi, xi, 0x128, 0xf, 0xf, true))); // row_ror:8
    xi = __builtin_bit_cast(int, x);
    x = fmaxf(x, __builtin_bit_cast(float, __builtin_amdgcn_update_dpp(xi, xi, 0x124, 0xf, 0xf, true))); // row_ror:4
    xi = __builtin_bit_cast(int, x);
    x = fmaxf(x, __builtin_bit_cast(float, __builtin_amdgcn_update_dpp(xi, xi, 0x122, 0xf, 0xf, true))); // row_ror:2
    xi = __builtin_bit_cast(int, x);
    x = fmaxf(x, __builtin_bit_cast(float, __builtin_amdgcn_update_dpp(xi, xi, 0x121, 0xf, 0xf, true))); // row_ror:1
    return x;
}

// ---------------- GroupNorm partial sums ----------------
__global__ __launch_bounds__(256) void gn_partial_kernel(const float* __restrict__ x,
                                                         float* __restrict__ statsraw) {
    int blk = blockIdx.x;                 // 0..255
    int t = threadIdx.x;
    size_t row0 = (size_t)blk * 64;
    int qd = t & 127;
    int rh = t >> 7;
    const float* base = x + row0 * 512 + qd * 4;
    float s1 = 0.f, s2 = 0.f;
    #pragma unroll 4
    for (int i = 0; i < 32; ++i) {
        int r = rh + i * 2;
        float4 v = *reinterpret_cast<const float4*>(base + (size_t)r * 512);
        s1 += v.x + v.y + v.z + v.w;
        s2 += v.x * v.x + v.y * v.y + v.z * v.z + v.w * v.w;
    }
    __shared__ float a1[256], a2[256];
    a1[t] = s1; a2[t] = s2;
    __syncthreads();
    if (t < 32) {
        float u1 = 0.f, u2 = 0.f;
        #pragma unroll
        for (int e = 0; e < 4; ++e) {
            u1 += a1[t * 4 + e] + a1[128 + t * 4 + e];
            u2 += a2[t * 4 + e] + a2[128 + t * 4 + e];
        }
        int b = (int)(row0 >> 12);
        atomicAdd(&statsraw[(b * 32 + t) * 2],     u1);
        atomicAdd(&statsraw[(b * 32 + t) * 2 + 1], u2);
    }
}

// ---------------- GroupNorm apply ----------------
__global__ __launch_bounds__(256) void gn_apply_kernel(const float* __restrict__ x,
                                                       const float* __restrict__ statsraw,
                                                       const float* __restrict__ gsc,
                                                       const float* __restrict__ gbs,
                                                       short* __restrict__ xn) {
    int i4 = blockIdx.x * 256 + threadIdx.x;
    int base = i4 * 4;
    int b = base >> 21;
    int c = base & 511;
    int sidx = (b * 32 + (c >> 4)) * 2;
    float s1 = statsraw[sidx], s2 = statsraw[sidx + 1];
    float mean = s1 * (1.f / 65536.f);
    float var  = s2 * (1.f / 65536.f) - mean * mean;
    float rstd = rsqrtf(var + GEPS);
    float4 xv = reinterpret_cast<const float4*>(x)[i4];
    float4 sv = *reinterpret_cast<const float4*>(gsc + c);
    float4 bv = *reinterpret_cast<const float4*>(gbs + c);
    union { short s[4]; uint2 u; } p;
    p.s[0] = bf16b((xv.x - mean) * rstd * sv.x + bv.x);
    p.s[1] = bf16b((xv.y - mean) * rstd * sv.y + bv.y);
    p.s[2] = bf16b((xv.z - mean) * rstd * sv.z + bv.z);
    p.s[3] = bf16b((xv.w - mean) * rstd * sv.w + bv.w);
    reinterpret_cast<uint2*>(xn)[i4] = p.u;
}

// ---------------- weight transpose ----------------
__global__ __launch_bounds__(256) void wtrans_kernel(const float* __restrict__ w0,
                                                     const float* __restrict__ w1,
                                                     const float* __restrict__ w2,
                                                     const float* __restrict__ w3,
                                                     short* __restrict__ wT) {
    const float* w = (blockIdx.z == 0) ? w0 : (blockIdx.z == 1) ? w1
                   : (blockIdx.z == 2) ? w2 : w3;
    short* out = wT + (size_t)blockIdx.z * CH * CH;
    int n0 = blockIdx.x * 32, k0 = blockIdx.y * 32;
    int tx = threadIdx.x, ty = threadIdx.y;
    __shared__ float s[32][33];
    #pragma unroll
    for (int i = 0; i < 4; ++i) {
        int kk = ty + i * 8;
        s[kk][tx] = w[(size_t)(k0 + kk) * CH + n0 + tx];
    }
    __syncthreads();
    #pragma unroll
    for (int i = 0; i < 4; ++i) {
        int nn = ty + i * 8;
        out[(size_t)(n0 + nn) * CH + k0 + tx] = bf16b(s[tx][nn]);
    }
}

// ---------------- fused QKV GEMM: fp8 epilogue ------------------------------------
// q8 row-major.
// k8 pair-interleaved tile layout (16KB per 32-row s-block), for flash's paired
//   b128 K reads: byte(b,s,d) = b*2M + (s>>5)*16384 + (s&15)*1024
//                               + (d>>3)*16 + ((s>>4)&1)*8 + (d&7)
//   -> a 16B slot holds chunk d/8 of rows s and s+16.
// vT8 s-col-interleaved (P order) AND pair-interleaved tile layout
//   (16KB per 32-s block): byte(b,d,si) = b*2M + (si>>5)*16384
//     + (((d>>5)*16 + (d&15))*4 + ((si&31)>>3))*16 + ((d>>4)&1)*8 + (si&7)
//   -> a 16B slot holds s-chunk m of rows d and d+16.
__global__ __launch_bounds__(256) void gemm_qkv_kernel(const short* __restrict__ A,
                                                       const short* __restrict__ wT,
                                                       const float* __restrict__ bq,
                                                       const float* __restrict__ bk,
                                                       const float* __restrict__ bv,
                                                       char* __restrict__ q8,
                                                       char* __restrict__ k8,
                                                       char* __restrict__ vT8) {
    __shared__ short As[128 * 64];
    __shared__ short Bs[128 * 64];
    __shared__ char  vls[128 * 144];   // fp8 transpose staging, pitch 144
    int m0 = blockIdx.x * 128;
    int nblk = blockIdx.y;                  // 0..11
    int which = nblk >> 2;                  // 0=q,1=k,2=v (block-uniform)
    int n0 = (nblk & 3) * 128;
    const short* BT = wT + (size_t)which * 512 * 512;
    const float* bias = (which == 0) ? bq : (which == 1) ? bk : bv;
    int t = threadIdx.x;
    int w = t >> 6, lane = t & 63;
    int wr = w >> 1, wc = w & 1;
    int l15 = lane & 15, l4 = lane >> 4;
    floatx4 acc[4][4];
    #pragma unroll
    for (int i = 0; i < 4; ++i)
        #pragma unroll
        for (int j = 0; j < 4; ++j) acc[i][j] = (floatx4){0.f, 0.f, 0.f, 0.f};

    for (int k0 = 0; k0 < 512; k0 += 64) {
        __syncthreads();
        #pragma unroll
        for (int i = 0; i < 4; ++i) {
            int c = i * 256 + t;
            int row = c >> 3, j = (c & 7) ^ (row & 7);
            dma16(&A[(size_t)(m0 + row) * 512 + k0 + j * 8], &As[(c & ~63) * 8]);
            dma16(&BT[(size_t)(n0 + row) * 512 + k0 + j * 8], &Bs[(c & ~63) * 8]);
        }
        __syncthreads();
        #pragma unroll
        for (int kk = 0; kk < 64; kk += 32) {
            short8 af[4], bf[4];
            #pragma unroll
            for (int i = 0; i < 4; ++i) {
                int row = wr * 64 + i * 16 + l15;
                int j = (kk >> 3) + l4;
                af[i] = *reinterpret_cast<const short8*>(&As[(row * 8 + (j ^ (l15 & 7))) * 8]);
            }
            #pragma unroll
            for (int j2 = 0; j2 < 4; ++j2) {
                int row = wc * 64 + j2 * 16 + l15;
                int j = (kk >> 3) + l4;
                bf[j2] = *reinterpret_cast<const short8*>(&Bs[(row * 8 + (j ^ (l15 & 7))) * 8]);
            }
            #pragma unroll
            for (int i = 0; i < 4; ++i)
                #pragma unroll
                for (int j2 = 0; j2 < 4; ++j2)
                    acc[i][j2] = __builtin_amdgcn_mfma_f32_16x16x32_bf16(af[i], bf[j2], acc[i][j2], 0, 0, 0);
        }
    }
    if (which == 0) {
        #pragma unroll
        for (int i = 0; i < 4; ++i)
            #pragma unroll
            for (int j = 0; j < 4; ++j)
                #pragma unroll
                for (int r = 0; r < 4; ++r) {
                    int row = m0 + wr * 64 + i * 16 + l4 * 4 + r;
                    int col = n0 + wc * 64 + j * 16 + l15;
                    q8[(size_t)row * 512 + col] = fp8b(acc[i][j][r] + bias[col]);
                }
    } else if (which == 1) {
        // k8: pair-interleaved tile layout (see header comment)
        #pragma unroll
        for (int i = 0; i < 4; ++i)
            #pragma unroll
            for (int j = 0; j < 4; ++j)
                #pragma unroll
                for (int r = 0; r < 4; ++r) {
                    int row = m0 + wr * 64 + i * 16 + l4 * 4 + r;
                    int col = n0 + wc * 64 + j * 16 + l15;
                    int bb = row >> 12, s = row & 4095;
                    size_t idx = (size_t)bb * 2097152 + (size_t)(s >> 5) * 16384
                               + (s & 15) * 1024 + ((s >> 4) & 1) * 8
                               + (col >> 3) * 16 + (col & 7);
                    k8[idx] = fp8b(acc[i][j][r] + bias[col]);
                }
    } else {
        // v: transpose via LDS, with s-columns pair-interleaved per 32-block
        __syncthreads();
        #pragma unroll
        for (int i = 0; i < 4; ++i)
            #pragma unroll
            for (int j = 0; j < 4; ++j)
                #pragma unroll
                for (int r = 0; r < 4; ++r) {
                    int rl = wr * 64 + i * 16 + l4 * 4 + r;     // local row (sequence)
                    int rp = (rl & ~31) | (((rl & 15) << 1) | ((rl >> 4) & 1));  // interleave
                    int cl = wc * 64 + j * 16 + l15;            // local col (d)
                    vls[cl * 144 + rp] = fp8b(acc[i][j][r] + bias[n0 + cl]);
                }
        __syncthreads();
        int b = m0 >> 12, l0 = m0 & 4095;
        #pragma unroll
        for (int p = 0; p < 4; ++p) {
            int slot = p * 256 + t;
            int c = slot >> 3, off = (slot & 7) * 16;   // off multiple of 16
            uint4 v;
            __builtin_memcpy(&v, &vls[c * 144 + off], 16);
            int dcol = n0 + c;
            int g = dcol >> 5, rr = dcol & 15, h = (dcol >> 4) & 1;
            int s = l0 + off;                    // interleaved s index, mult of 16
            int sb = s >> 5, mb = (s & 31) >> 3; // mb = 0 or 2
            char* dst = vT8 + (size_t)b * 2097152 + (size_t)sb * 16384
                      + (size_t)((((g * 16 + rr) * 4 + mb) * 16) + h * 8);
            unsigned long long lo = ((unsigned long long)v.y << 32) | v.x;
            unsigned long long hi = ((unsigned long long)v.w << 32) | v.z;
            *reinterpret_cast<unsigned long long*>(dst)      = lo;  // chunk mb
            *reinterpret_cast<unsigned long long*>(dst + 16) = hi;  // chunk mb+1
        }
    }
}

// ---------------- output GEMM with FUSED combine: A = merge(Opart0, Opart1, ml) ------
// NOTE: ml max values are in BASE-2 units (flash computes softmax with exp2),
// so the merge uses exp2f.
__global__ __launch_bounds__(256) void gemm_bt_kernel(const short* __restrict__ Opart,
                                                      const float* __restrict__ ml,
                                                      const short* __restrict__ BT,
                                                      const float* __restrict__ bias,
                                                      float* __restrict__ outf,
                                                      const float* __restrict__ resid) {
    __shared__ short As[128 * 64];
    __shared__ short Bs[128 * 64];
    int m0 = blockIdx.x * 128, n0 = blockIdx.y * 128;
    int t = threadIdx.x;
    int w = t >> 6, lane = t & 63;
    int wr = w >> 1, wc = w & 1;
    int l15 = lane & 15, l4 = lane >> 4;
    const size_t PART = (size_t)BATCH * SEQ;   // 16384 rows per part
    floatx4 acc[4][4];
    #pragma unroll
    for (int i = 0; i < 4; ++i)
        #pragma unroll
        for (int j = 0; j < 4; ++j) acc[i][j] = (floatx4){0.f, 0.f, 0.f, 0.f};

    for (int k0 = 0; k0 < 512; k0 += 64) {
        __syncthreads();
        #pragma unroll
        for (int i = 0; i < 4; ++i) {
            int c = i * 256 + t;
            int rl = c >> 3, j = (c & 7) ^ (rl & 7);
            size_t rowg = (size_t)(m0 + rl);
            const short* s0 = Opart + rowg * 512 + k0 + j * 8;
            const short* s1 = s0 + PART * 512;
            uint4 a0 = *reinterpret_cast<const uint4*>(s0);
            uint4 a1 = *reinterpret_cast<const uint4*>(s1);
            float mA = ml[rowg * 2],          lA = ml[rowg * 2 + 1];
            float mB = ml[(PART + rowg) * 2], lB = ml[(PART + rowg) * 2 + 1];
            float mm = fmaxf(mA, mB);
            float e0 = exp2f(mA - mm), e1 = exp2f(mB - mm);
            float inv = 1.f / (e0 * lA + e1 * lB);
            e0 *= inv; e1 *= inv;
            union { uint4 u; short s[8]; } ua, ub, uo;
            ua.u = a0; ub.u = a1;
            #pragma unroll
            for (int e = 0; e < 8; ++e)
                uo.s[e] = bf16b(bf2f(ua.s[e]) * e0 + bf2f(ub.s[e]) * e1);
            *reinterpret_cast<uint4*>(&As[c * 8]) = uo.u;    // ds_write_b128
            dma16(&BT[(size_t)(n0 + rl) * 512 + k0 + j * 8], &Bs[(c & ~63) * 8]);
        }
        __syncthreads();
        #pragma unroll
        for (int kk = 0; kk < 64; kk += 32) {
            short8 af[4], bf[4];
            #pragma unroll
            for (int i = 0; i < 4; ++i) {
                int row = wr * 64 + i * 16 + l15;
                int j = (kk >> 3) + l4;
                af[i] = *reinterpret_cast<const short8*>(&As[(row * 8 + (j ^ (l15 & 7))) * 8]);
            }
            #pragma unroll
            for (int j2 = 0; j2 < 4; ++j2) {
                int row = wc * 64 + j2 * 16 + l15;
                int j = (kk >> 3) + l4;
                bf[j2] = *reinterpret_cast<const short8*>(&Bs[(row * 8 + (j ^ (l15 & 7))) * 8]);
            }
            #pragma unroll
            for (int i = 0; i < 4; ++i)
                #pragma unroll
                for (int j2 = 0; j2 < 4; ++j2)
                    acc[i][j2] = __builtin_amdgcn_mfma_f32_16x16x32_bf16(af[i], bf[j2], acc[i][j2], 0, 0, 0);
        }
    }
    #pragma unroll
    for (int i = 0; i < 4; ++i)
        #pragma unroll
        for (int j = 0; j < 4; ++j)
            #pragma unroll
            for (int r = 0; r < 4; ++r) {
                int row = m0 + wr * 64 + i * 16 + l4 * 4 + r;
                int col = n0 + wc * 64 + j * 16 + l15;
                float vv = acc[i][j][r] + bias[col];
                outf[(size_t)row * 512 + col] = vv + resid[(size_t)row * 512 + col];
            }
}

// ---------------- flash attention: fp8, lagged-PV pipeline ---------------------------
// Structure: per iter, PV of tile it-1 (pure MFMA, P held in registers) shares one
// scheduling region with softmax of tile it (pure VALU) -> in-wave MFMA/VALU overlap.
// Buffers: K single (16K, restaged mid-iter under PV||sm), V triple (48K), P 2.5K
// = 68096 B -> still 2 blocks/CU; the 2 blocks stay desynchronized.
// Barrier ledger (2 bars/iter):
//   Kbuf: read by QK^T(it) pre-bar1(it); stageK(it+1) issued post-bar1(it),
//         drained at bar2(it); read QK^T(it+1) post-bar2(it).                OK
//   Vbuf j=(it+1)%3: stageV issued top of iter it (pre-bar1), drained bar2(it);
//         read by PV(it) in iter it+1 (post-bar2(it)).                       OK
//   Vbuf j=(it-1)%3: read by PV(it-1) in [bar1,bar2](it); overwritten by
//         stageV(it+2) issued top of iter it+1 = post-bar2(it).              OK
//   P: per-wave private; write->read same wave ordered by lgkmcnt+alias.     OK
// Softmax is base-2 end-to-end (c2 folds 1/sqrt(512)*log2e); ml stores base-2 m.
__global__ __launch_bounds__(256, 2) void flash_kernel(const char* __restrict__ q8,
                                                       const char* __restrict__ k8,
                                                       const char* __restrict__ v8,
                                                       short* __restrict__ Opart,
                                                       float* __restrict__ ml) {
    __shared__ __align__(16) char smem[68096];   // K 16K | V 3x16K | P 2.5K
    int bx = blockIdx.x;                 // 0..511
    int pb = bx & 7;                     // XCD-local (part,b)
    int part = pb >> 2, b = pb & 3;
    int q0 = (bx >> 3) * 64;
    int t = threadIdx.x, w = t >> 6, lane = t & 63;
    int l15 = lane & 15, l4 = lane >> 4;
    const float c2 = 0.06375873735f;     // (1/sqrt(512)) * log2(e)
    const float MARGIN = 7.2134752f;     // 5 * log2(e); p <= 2^7.21 = 148 < 448

    // Q fp8 fragments: rows w*16 + l15, all 512 k (8 B per ks-step)
    long qf[16];
    {
        const char* qrow = q8 + ((size_t)b * SEQ + q0 + w * 16 + l15) * 512;
        #pragma unroll
        for (int ks = 0; ks < 16; ++ks)
            qf[ks] = *reinterpret_cast<const long*>(qrow + ks * 32 + l4 * 8);
    }

    floatx4 acc[32];
    #pragma unroll
    for (int i = 0; i < 32; ++i) acc[i] = (floatx4){0.f, 0.f, 0.f, 0.f};
    floatx4 lacc = (floatx4){0.f, 0.f, 0.f, 0.f};
    float mused[4] = {-1e30f, -1e30f, -1e30f, -1e30f};

    const long ones = 0x3838383838383838L;   // e4m3 1.0 x8

    const char* kbase = k8 + (size_t)b * SEQ * 512;
    const char* vbase = v8 + (size_t)b * 512 * SEQ;
    const int sb0 = part * 64;           // first 32-s block of this part

    const int ksw = l15 & 7;
    const int vsw = (l15 >> 1) & 3;
    // loop-invariant LDS addresses (K single-buffered at smem+0):
    //   K slot(r,m) = r*64 + (m ^ (r&7)); ks=2j -> E-base + j*128, ks=2j+1 -> O-base
    const char* kAddrE = smem + ((l15 * 64 + (l4 ^ ksw)) << 4);
    const char* kAddrO = smem + ((l15 * 64 + ((4 + l4) ^ ksw)) << 4);
    const int vLane = (l15 * 4 + (l4 ^ vsw)) << 4;
    char* Ps = smem + 65536 + w * 640;

    auto stageK = [&](int sb) {
        const char* kt = kbase + (size_t)sb * 16384;
        #pragma unroll
        for (int i = 0; i < 4; ++i) {
            int c = i * 256 + t;
            int src = (c & ~63) | ((c & 63) ^ ((c >> 6) & 7));
            dma16(kt + (size_t)src * 16, smem + (size_t)(c & ~63) * 16);
        }
    };
    auto stageV = [&](int sb, int vOff) {
        const char* vt = vbase + (size_t)sb * 16384;
        char* Vd = smem + vOff;
        #pragma unroll
        for (int i = 0; i < 4; ++i) {
            int c = i * 256 + t;
            int src = (c & ~3) | ((c & 3) ^ ((c >> 3) & 3));
            dma16(vt + (size_t)src * 16, Vd + (size_t)(c & ~63) * 16);
        }
    };
    auto qkt = [&](floatx4& sa0, floatx4& sa1) {
        __builtin_amdgcn_s_setprio(1);
        #pragma unroll
        for (int j = 0; j < 8; ++j) {
            longx2 kE = *reinterpret_cast<const longx2*>(kAddrE + j * 128);
            longx2 kO = *reinterpret_cast<const longx2*>(kAddrO + j * 128);
            sa0 = __builtin_amdgcn_mfma_f32_16x16x32_fp8_fp8(qf[2 * j],     kE[0], sa0, 0, 0, 0);
            sa1 = __builtin_amdgcn_mfma_f32_16x16x32_fp8_fp8(qf[2 * j],     kE[1], sa1, 0, 0, 0);
            sa0 = __builtin_amdgcn_mfma_f32_16x16x32_fp8_fp8(qf[2 * j + 1], kO[0], sa0, 0, 0, 0);
            sa1 = __builtin_amdgcn_mfma_f32_16x16x32_fp8_fp8(qf[2 * j + 1], kO[1], sa1, 0, 0, 0);
        }
        __builtin_amdgcn_s_setprio(0);
    };
    auto pv = [&](long pfv, int vRd) {
        __builtin_amdgcn_s_setprio(1);
        lacc = __builtin_amdgcn_mfma_f32_16x16x32_fp8_fp8(pfv, ones, lacc, 0, 0, 0);
        const char* Vb = smem + vRd;
        #pragma unroll
        for (int g = 0; g < 16; ++g) {
            longx2 vv = *reinterpret_cast<const longx2*>(Vb + vLane + g * 1024);
            acc[2 * g]     = __builtin_amdgcn_mfma_f32_16x16x32_fp8_fp8(pfv, vv[0], acc[2 * g],     0, 0, 0);
            acc[2 * g + 1] = __builtin_amdgcn_mfma_f32_16x16x32_fp8_fp8(pfv, vv[1], acc[2 * g + 1], 0, 0, 0);
        }
        __builtin_amdgcn_s_setprio(0);
    };
    // softmax(it): VALU-only; speculative exp with current mused so the common
    // (no-rescale) path is branch-free and can interleave with pv()'s MFMAs.
    auto softmax = [&](floatx4 sa0, floatx4 sa1) -> long {
        float v0[4], v1[4], nm4[4];
        bool need = false;
        #pragma unroll
        for (int r = 0; r < 4; ++r) {
            v0[r] = sa0[r] * c2; v1[r] = sa1[r] * c2;
            nm4[r] = rowmax16(fmaxf(v0[r], v1[r]));
            need |= (nm4[r] > mused[r] + MARGIN);
        }
        #pragma unroll
        for (int r = 0; r < 4; ++r) {
            int pk = __builtin_amdgcn_cvt_pk_fp8_f32(exp2f(v0[r] - mused[r]),
                                                     exp2f(v1[r] - mused[r]), 0, false);
            *reinterpret_cast<short*>(Ps + (l4 * 4 + r) * 40 + l15 * 2) = (short)pk;
        }
        if (__ballot(need)) {
            #pragma unroll
            for (int r = 0; r < 4; ++r) {
                float nm = fmaxf(mused[r], nm4[r]);
                float al = exp2f(mused[r] - nm);
                lacc[r] *= al;
                #pragma unroll
                for (int i = 0; i < 32; ++i) acc[i][r] *= al;
                mused[r] = nm;
                int pk = __builtin_amdgcn_cvt_pk_fp8_f32(exp2f(v0[r] - nm),
                                                         exp2f(v1[r] - nm), 0, false);
                *reinterpret_cast<short*>(Ps + (l4 * 4 + r) * 40 + l15 * 2) = (short)pk;
            }
        }
        // A-frag read via memcpy (may-alias pun -> ordered AFTER the short stores)
        long pfv;
        __builtin_memcpy(&pfv, (const char*)__builtin_assume_aligned(Ps + l15 * 40 + l4 * 8, 8), 8);
        return pfv;
    };

    // prologue: tile 0 (K + V->buf0)
    stageV(sb0, 16384);
    stageK(sb0);
    asm volatile("s_waitcnt vmcnt(0)" ::: "memory");
    __syncthreads();

    long pf;
    // ---- peeled it = 0 (no PV) ----
    {
        stageV(sb0 + 1, 32768);
        floatx4 sa0 = (floatx4){0.f, 0.f, 0.f, 0.f};
        floatx4 sa1 = (floatx4){0.f, 0.f, 0.f, 0.f};
        qkt(sa0, sa1);
        __syncthreads();                                 // bar1: K free
        stageK(sb0 + 1);
        pf = softmax(sa0, sa1);
        asm volatile("s_waitcnt vmcnt(0)" ::: "memory");
        __syncthreads();                                 // bar2
    }
    int vRd = 16384;           // buf of tile it-1
    int vWr = 49152;           // buf for tile it+1
    for (int it = 1; it < 64; ++it) {
        if (it + 1 < 64) stageV(sb0 + it + 1, vWr);
        floatx4 sa0 = (floatx4){0.f, 0.f, 0.f, 0.f};
        floatx4 sa1 = (floatx4){0.f, 0.f, 0.f, 0.f};
        qkt(sa0, sa1);
        __syncthreads();                                 // bar1: K free
        if (it + 1 < 64) stageK(sb0 + it + 1);
        pv(pf, vRd);                                     // MFMA, tile it-1
        pf = softmax(sa0, sa1);                          // VALU, tile it (interleaves)
        asm volatile("s_waitcnt vmcnt(0)" ::: "memory");
        __syncthreads();                                 // bar2: next tile ready
        vRd = (vRd == 49152) ? 16384 : vRd + 16384;
        vWr = (vWr == 49152) ? 16384 : vWr + 16384;
    }
    pv(pf, vRd);                                         // PV(63), buf 63%3=0

    short* obase = Opart + (((size_t)part * BATCH + b) * SEQ + q0 + w * 16) * 512;
    #pragma unroll
    for (int r = 0; r < 4; ++r) {
        #pragma unroll
        for (int tt = 0; tt < 32; ++tt)
            obase[(size_t)(l4 * 4 + r) * 512 + tt * 16 + l15] = bf16b(acc[tt][r]);
    }
    if (l15 == 0) {
        #pragma unroll
        for (int r = 0; r < 4; ++r) {
            size_t rowg = ((size_t)part * BATCH + b) * SEQ + q0 + w * 16 + l4 * 4 + r;
            ml[rowg * 2]     = mused[r];      // base-2 units
            ml[rowg * 2 + 1] = lacc[r];
        }
    }
}

extern "C" void kernel_launch(void* const* d_in, const int* in_sizes, int n_in,
                              void* d_out, int out_size, void* d_ws, size_t ws_size,
                              hipStream_t stream) {
    const float* x   = (const float*)d_in[0];
    const float* gsc = (const float*)d_in[1];
    const float* gbs = (const float*)d_in[2];
    const float* wq  = (const float*)d_in[3];
    const float* bq  = (const float*)d_in[4];
    const float* wk  = (const float*)d_in[5];
    const float* bk  = (const float*)d_in[6];
    const float* wv  = (const float*)d_in[7];
    const float* bv  = (const float*)d_in[8];
    const float* wo  = (const float*)d_in[9];
    const float* bo  = (const float*)d_in[10];
    float* out = (float*)d_out;

    char* ws = (char*)d_ws;
    const size_t MB = 1ull << 20;
    // [0,16)  xn bf16 (GEMM A input, dead after QKV GEMM)
    // [16,24) q8; [24,32) k8; [32,40) vT8 (fp8, from gemm_qkv epilogue)
    // [40,72) Opart bf16 (2 parts); [72,74) wT; [74,..) stats + ml
    short* xn    = (short*)ws;
    char*  q8    = (char*)(ws + 16 * MB);
    char*  k8    = (char*)(ws + 24 * MB);
    char*  vT8   = (char*)(ws + 32 * MB);
    short* Opart = (short*)(ws + 40 * MB);
    short* wT    = (short*)(ws + 72 * MB);
    float* stats = (float*)(ws + 74 * MB);
    float* ml    = (float*)(ws + 74 * MB + 65536);

    hipMemsetAsync(stats, 0, 256 * sizeof(float), stream);
    gn_partial_kernel<<<256, 256, 0, stream>>>(x, stats);
    gn_apply_kernel<<<8192, 256, 0, stream>>>(x, stats, gsc, gbs, xn);
    wtrans_kernel<<<dim3(16, 16, 4), dim3(32, 8), 0, stream>>>(wq, wk, wv, wo, wT);

    short* woT = wT + 786432;

    gemm_qkv_kernel<<<dim3(128, 12), 256, 0, stream>>>(xn, wT, bq, bk, bv, q8, k8, vT8);
    flash_kernel<<<512, 256, 0, stream>>>(q8, k8, vT8, Opart, ml);
    gemm_bt_kernel<<<dim3(128, 4), 256, 0, stream>>>(Opart, ml, woT, bo, out, x);
}

// Round 4
// 292.853 us; speedup vs baseline: 1.0066x; 1.0066x over previous
//
#include <hip/hip_runtime.h>
#include <hip/hip_bf16.h>
#include <stdint.h>

#define BATCH 4
#define SEQ   4096          // 64*64 spatial
#define CH    512
#define NGRP  32
#define GEPS  1e-6f

typedef short  short8  __attribute__((ext_vector_type(8)));
typedef float  floatx4 __attribute__((ext_vector_type(4)));
typedef long   longx2  __attribute__((ext_vector_type(2)));

static __device__ __forceinline__ short bf16b(float f) {
    __hip_bfloat16 h = __float2bfloat16(f);
    return __builtin_bit_cast(short, h);
}
static __device__ __forceinline__ float bf2f(short s) {
    unsigned u = ((unsigned)(unsigned short)s) << 16;
    return __builtin_bit_cast(float, u);
}
static __device__ __forceinline__ char fp8b(float f) {
    int pk = __builtin_amdgcn_cvt_pk_fp8_f32(f, f, 0, false);
    return (char)(pk & 0xff);
}

// async global->LDS, 16B per lane. LDS dest = wave-uniform base + lane*16.
static __device__ __forceinline__ void dma16(const void* g, void* l) {
    __builtin_amdgcn_global_load_lds(
        (const __attribute__((address_space(1))) unsigned int*)g,
        (__attribute__((address_space(3))) unsigned int*)l, 16, 0, 0);
}

// max-reduce across the 16 lanes of a DPP row, pure VALU
static __device__ __forceinline__ float rowmax16(float x) {
    int xi = __builtin_bit_cast(int, x);
    x = fmaxf(x, __builtin_bit_cast(float, __builtin_amdgcn_update_dpp(xi, xi, 0x128, 0xf, 0xf, true))); // row_ror:8
    xi = __builtin_bit_cast(int, x);
    x = fmaxf(x, __builtin_bit_cast(float, __builtin_amdgcn_update_dpp(xi, xi, 0x124, 0xf, 0xf, true))); // row_ror:4
    xi = __builtin_bit_cast(int, x);
    x = fmaxf(x, __builtin_bit_cast(float, __builtin_amdgcn_update_dpp(xi, xi, 0x122, 0xf, 0xf, true))); // row_ror:2
    xi = __builtin_bit_cast(int, x);
    x = fmaxf(x, __builtin_bit_cast(float, __builtin_amdgcn_update_dpp(xi, xi, 0x121, 0xf, 0xf, true))); // row_ror:1
    return x;
}

// ---------------- GroupNorm partial sums ----------------
__global__ __launch_bounds__(256) void gn_partial_kernel(const float* __restrict__ x,
                                                         float* __restrict__ statsraw) {
    int blk = blockIdx.x;                 // 0..255
    int t = threadIdx.x;
    size_t row0 = (size_t)blk * 64;
    int qd = t & 127;
    int rh = t >> 7;
    const float* base = x + row0 * 512 + qd * 4;
    float s1 = 0.f, s2 = 0.f;
    #pragma unroll 4
    for (int i = 0; i < 32; ++i) {
        int r = rh + i * 2;
        float4 v = *reinterpret_cast<const float4*>(base + (size_t)r * 512);
        s1 += v.x + v.y + v.z + v.w;
        s2 += v.x * v.x + v.y * v.y + v.z * v.z + v.w * v.w;
    }
    __shared__ float a1[256], a2[256];
    a1[t] = s1; a2[t] = s2;
    __syncthreads();
    if (t < 32) {
        float u1 = 0.f, u2 = 0.f;
        #pragma unroll
        for (int e = 0; e < 4; ++e) {
            u1 += a1[t * 4 + e] + a1[128 + t * 4 + e];
            u2 += a2[t * 4 + e] + a2[128 + t * 4 + e];
        }
        int b = (int)(row0 >> 12);
        atomicAdd(&statsraw[(b * 32 + t) * 2],     u1);
        atomicAdd(&statsraw[(b * 32 + t) * 2 + 1], u2);
    }
}

// ---------------- GroupNorm apply ----------------
__global__ __launch_bounds__(256) void gn_apply_kernel(const float* __restrict__ x,
                                                       const float* __restrict__ statsraw,
                                                       const float* __restrict__ gsc,
                                                       const float* __restrict__ gbs,
                                                       short* __restrict__ xn) {
    int i4 = blockIdx.x * 256 + threadIdx.x;
    int base = i4 * 4;
    int b = base >> 21;
    int c = base & 511;
    int sidx = (b * 32 + (c >> 4)) * 2;
    float s1 = statsraw[sidx], s2 = statsraw[sidx + 1];
    float mean = s1 * (1.f / 65536.f);
    float var  = s2 * (1.f / 65536.f) - mean * mean;
    float rstd = rsqrtf(var + GEPS);
    float4 xv = reinterpret_cast<const float4*>(x)[i4];
    float4 sv = *reinterpret_cast<const float4*>(gsc + c);
    float4 bv = *reinterpret_cast<const float4*>(gbs + c);
    union { short s[4]; uint2 u; } p;
    p.s[0] = bf16b((xv.x - mean) * rstd * sv.x + bv.x);
    p.s[1] = bf16b((xv.y - mean) * rstd * sv.y + bv.y);
    p.s[2] = bf16b((xv.z - mean) * rstd * sv.z + bv.z);
    p.s[3] = bf16b((xv.w - mean) * rstd * sv.w + bv.w);
    reinterpret_cast<uint2*>(xn)[i4] = p.u;
}

// ---------------- weight transpose ----------------
__global__ __launch_bounds__(256) void wtrans_kernel(const float* __restrict__ w0,
                                                     const float* __restrict__ w1,
                                                     const float* __restrict__ w2,
                                                     const float* __restrict__ w3,
                                                     short* __restrict__ wT) {
    const float* w = (blockIdx.z == 0) ? w0 : (blockIdx.z == 1) ? w1
                   : (blockIdx.z == 2) ? w2 : w3;
    short* out = wT + (size_t)blockIdx.z * CH * CH;
    int n0 = blockIdx.x * 32, k0 = blockIdx.y * 32;
    int tx = threadIdx.x, ty = threadIdx.y;
    __shared__ float s[32][33];
    #pragma unroll
    for (int i = 0; i < 4; ++i) {
        int kk = ty + i * 8;
        s[kk][tx] = w[(size_t)(k0 + kk) * CH + n0 + tx];
    }
    __syncthreads();
    #pragma unroll
    for (int i = 0; i < 4; ++i) {
        int nn = ty + i * 8;
        out[(size_t)(n0 + nn) * CH + k0 + tx] = bf16b(s[tx][nn]);
    }
}

// ---------------- fused QKV GEMM: fp8 epilogue ------------------------------------
// q8 row-major.
// k8 pair-interleaved tile layout (16KB per 32-row s-block), for flash's paired
//   b128 K reads: byte(b,s,d) = b*2M + (s>>5)*16384 + (s&15)*1024
//                               + (d>>3)*16 + ((s>>4)&1)*8 + (d&7)
//   -> a 16B slot holds chunk d/8 of rows s and s+16.
// vT8 s-col-interleaved (P order) AND pair-interleaved tile layout
//   (16KB per 32-s block): byte(b,d,si) = b*2M + (si>>5)*16384
//     + (((d>>5)*16 + (d&15))*4 + ((si&31)>>3))*16 + ((d>>4)&1)*8 + (si&7)
//   -> a 16B slot holds s-chunk m of rows d and d+16.
__global__ __launch_bounds__(256) void gemm_qkv_kernel(const short* __restrict__ A,
                                                       const short* __restrict__ wT,
                                                       const float* __restrict__ bq,
                                                       const float* __restrict__ bk,
                                                       const float* __restrict__ bv,
                                                       char* __restrict__ q8,
                                                       char* __restrict__ k8,
                                                       char* __restrict__ vT8) {
    __shared__ short As[128 * 64];
    __shared__ short Bs[128 * 64];
    __shared__ char  vls[128 * 144];   // fp8 transpose staging, pitch 144
    int m0 = blockIdx.x * 128;
    int nblk = blockIdx.y;                  // 0..11
    int which = nblk >> 2;                  // 0=q,1=k,2=v (block-uniform)
    int n0 = (nblk & 3) * 128;
    const short* BT = wT + (size_t)which * 512 * 512;
    const float* bias = (which == 0) ? bq : (which == 1) ? bk : bv;
    int t = threadIdx.x;
    int w = t >> 6, lane = t & 63;
    int wr = w >> 1, wc = w & 1;
    int l15 = lane & 15, l4 = lane >> 4;
    floatx4 acc[4][4];
    #pragma unroll
    for (int i = 0; i < 4; ++i)
        #pragma unroll
        for (int j = 0; j < 4; ++j) acc[i][j] = (floatx4){0.f, 0.f, 0.f, 0.f};

    for (int k0 = 0; k0 < 512; k0 += 64) {
        __syncthreads();
        #pragma unroll
        for (int i = 0; i < 4; ++i) {
            int c = i * 256 + t;
            int row = c >> 3, j = (c & 7) ^ (row & 7);
            dma16(&A[(size_t)(m0 + row) * 512 + k0 + j * 8], &As[(c & ~63) * 8]);
            dma16(&BT[(size_t)(n0 + row) * 512 + k0 + j * 8], &Bs[(c & ~63) * 8]);
        }
        __syncthreads();
        #pragma unroll
        for (int kk = 0; kk < 64; kk += 32) {
            short8 af[4], bf[4];
            #pragma unroll
            for (int i = 0; i < 4; ++i) {
                int row = wr * 64 + i * 16 + l15;
                int j = (kk >> 3) + l4;
                af[i] = *reinterpret_cast<const short8*>(&As[(row * 8 + (j ^ (l15 & 7))) * 8]);
            }
            #pragma unroll
            for (int j2 = 0; j2 < 4; ++j2) {
                int row = wc * 64 + j2 * 16 + l15;
                int j = (kk >> 3) + l4;
                bf[j2] = *reinterpret_cast<const short8*>(&Bs[(row * 8 + (j ^ (l15 & 7))) * 8]);
            }
            #pragma unroll
            for (int i = 0; i < 4; ++i)
                #pragma unroll
                for (int j2 = 0; j2 < 4; ++j2)
                    acc[i][j2] = __builtin_amdgcn_mfma_f32_16x16x32_bf16(af[i], bf[j2], acc[i][j2], 0, 0, 0);
        }
    }
    if (which == 0) {
        #pragma unroll
        for (int i = 0; i < 4; ++i)
            #pragma unroll
            for (int j = 0; j < 4; ++j)
                #pragma unroll
                for (int r = 0; r < 4; ++r) {
                    int row = m0 + wr * 64 + i * 16 + l4 * 4 + r;
                    int col = n0 + wc * 64 + j * 16 + l15;
                    q8[(size_t)row * 512 + col] = fp8b(acc[i][j][r] + bias[col]);
                }
    } else if (which == 1) {
        // k8: pair-interleaved tile layout (see header comment)
        #pragma unroll
        for (int i = 0; i < 4; ++i)
            #pragma unroll
            for (int j = 0; j < 4; ++j)
                #pragma unroll
                for (int r = 0; r < 4; ++r) {
                    int row = m0 + wr * 64 + i * 16 + l4 * 4 + r;
                    int col = n0 + wc * 64 + j * 16 + l15;
                    int bb = row >> 12, s = row & 4095;
                    size_t idx = (size_t)bb * 2097152 + (size_t)(s >> 5) * 16384
                               + (s & 15) * 1024 + ((s >> 4) & 1) * 8
                               + (col >> 3) * 16 + (col & 7);
                    k8[idx] = fp8b(acc[i][j][r] + bias[col]);
                }
    } else {
        // v: transpose via LDS, with s-columns pair-interleaved per 32-block
        __syncthreads();
        #pragma unroll
        for (int i = 0; i < 4; ++i)
            #pragma unroll
            for (int j = 0; j < 4; ++j)
                #pragma unroll
                for (int r = 0; r < 4; ++r) {
                    int rl = wr * 64 + i * 16 + l4 * 4 + r;     // local row (sequence)
                    int rp = (rl & ~31) | (((rl & 15) << 1) | ((rl >> 4) & 1));  // interleave
                    int cl = wc * 64 + j * 16 + l15;            // local col (d)
                    vls[cl * 144 + rp] = fp8b(acc[i][j][r] + bias[n0 + cl]);
                }
        __syncthreads();
        int b = m0 >> 12, l0 = m0 & 4095;
        #pragma unroll
        for (int p = 0; p < 4; ++p) {
            int slot = p * 256 + t;
            int c = slot >> 3, off = (slot & 7) * 16;   // off multiple of 16
            uint4 v;
            __builtin_memcpy(&v, &vls[c * 144 + off], 16);
            int dcol = n0 + c;
            int g = dcol >> 5, rr = dcol & 15, h = (dcol >> 4) & 1;
            int s = l0 + off;                    // interleaved s index, mult of 16
            int sb = s >> 5, mb = (s & 31) >> 3; // mb = 0 or 2
            char* dst = vT8 + (size_t)b * 2097152 + (size_t)sb * 16384
                      + (size_t)((((g * 16 + rr) * 4 + mb) * 16) + h * 8);
            unsigned long long lo = ((unsigned long long)v.y << 32) | v.x;
            unsigned long long hi = ((unsigned long long)v.w << 32) | v.z;
            *reinterpret_cast<unsigned long long*>(dst)      = lo;  // chunk mb
            *reinterpret_cast<unsigned long long*>(dst + 16) = hi;  // chunk mb+1
        }
    }
}

// ---------------- output GEMM with FUSED combine: A = merge(Opart0, Opart1, ml) ------
// NOTE: ml max values are in BASE-2 units (flash computes softmax with exp2),
// so the merge uses exp2f.
__global__ __launch_bounds__(256) void gemm_bt_kernel(const short* __restrict__ Opart,
                                                      const float* __restrict__ ml,
                                                      const short* __restrict__ BT,
                                                      const float* __restrict__ bias,
                                                      float* __restrict__ outf,
                                                      const float* __restrict__ resid) {
    __shared__ short As[128 * 64];
    __shared__ short Bs[128 * 64];
    int m0 = blockIdx.x * 128, n0 = blockIdx.y * 128;
    int t = threadIdx.x;
    int w = t >> 6, lane = t & 63;
    int wr = w >> 1, wc = w & 1;
    int l15 = lane & 15, l4 = lane >> 4;
    const size_t PART = (size_t)BATCH * SEQ;   // 16384 rows per part
    floatx4 acc[4][4];
    #pragma unroll
    for (int i = 0; i < 4; ++i)
        #pragma unroll
        for (int j = 0; j < 4; ++j) acc[i][j] = (floatx4){0.f, 0.f, 0.f, 0.f};

    for (int k0 = 0; k0 < 512; k0 += 64) {
        __syncthreads();
        #pragma unroll
        for (int i = 0; i < 4; ++i) {
            int c = i * 256 + t;
            int rl = c >> 3, j = (c & 7) ^ (rl & 7);
            size_t rowg = (size_t)(m0 + rl);
            const short* s0 = Opart + rowg * 512 + k0 + j * 8;
            const short* s1 = s0 + PART * 512;
            uint4 a0 = *reinterpret_cast<const uint4*>(s0);
            uint4 a1 = *reinterpret_cast<const uint4*>(s1);
            float mA = ml[rowg * 2],          lA = ml[rowg * 2 + 1];
            float mB = ml[(PART + rowg) * 2], lB = ml[(PART + rowg) * 2 + 1];
            float mm = fmaxf(mA, mB);
            float e0 = exp2f(mA - mm), e1 = exp2f(mB - mm);
            float inv = 1.f / (e0 * lA + e1 * lB);
            e0 *= inv; e1 *= inv;
            union { uint4 u; short s[8]; } ua, ub, uo;
            ua.u = a0; ub.u = a1;
            #pragma unroll
            for (int e = 0; e < 8; ++e)
                uo.s[e] = bf16b(bf2f(ua.s[e]) * e0 + bf2f(ub.s[e]) * e1);
            *reinterpret_cast<uint4*>(&As[c * 8]) = uo.u;    // ds_write_b128
            dma16(&BT[(size_t)(n0 + rl) * 512 + k0 + j * 8], &Bs[(c & ~63) * 8]);
        }
        __syncthreads();
        #pragma unroll
        for (int kk = 0; kk < 64; kk += 32) {
            short8 af[4], bf[4];
            #pragma unroll
            for (int i = 0; i < 4; ++i) {
                int row = wr * 64 + i * 16 + l15;
                int j = (kk >> 3) + l4;
                af[i] = *reinterpret_cast<const short8*>(&As[(row * 8 + (j ^ (l15 & 7))) * 8]);
            }
            #pragma unroll
            for (int j2 = 0; j2 < 4; ++j2) {
                int row = wc * 64 + j2 * 16 + l15;
                int j = (kk >> 3) + l4;
                bf[j2] = *reinterpret_cast<const short8*>(&Bs[(row * 8 + (j ^ (l15 & 7))) * 8]);
            }
            #pragma unroll
            for (int i = 0; i < 4; ++i)
                #pragma unroll
                for (int j2 = 0; j2 < 4; ++j2)
                    acc[i][j2] = __builtin_amdgcn_mfma_f32_16x16x32_bf16(af[i], bf[j2], acc[i][j2], 0, 0, 0);
        }
    }
    #pragma unroll
    for (int i = 0; i < 4; ++i)
        #pragma unroll
        for (int j = 0; j < 4; ++j)
            #pragma unroll
            for (int r = 0; r < 4; ++r) {
                int row = m0 + wr * 64 + i * 16 + l4 * 4 + r;
                int col = n0 + wc * 64 + j * 16 + l15;
                float vv = acc[i][j][r] + bias[col];
                outf[(size_t)row * 512 + col] = vv + resid[(size_t)row * 512 + col];
            }
}

// ---------------- flash attention: fp8, round-2 structure + hoisted addressing ------
// Round-2 pipeline (K/V dbuf, 1 barrier/iter, 2 blocks/CU) with:
//  - all K/V ds_read addresses hoisted to 3 loop-invariant bases + immediate
//    offsets (the per-lane swizzle xor's bit-2 component folds into the E/O
//    bases: (8j+l4)^ksw == 8j + (l4^ksw) and (8j+4+l4)^ksw == 8j + ((4+l4)^ksw)
//    since l4<4). Per iter only one cur<<14 add.
//  - DMA source offsets precomputed per-thread (8 ints); LDS dests are
//    wave-uniform (i*4096 + w*1024).
//  - base-2 softmax end-to-end (c2 = log2e/sqrt(512)); ml stores base-2 m.
//  - s_setprio(1) around QK and PV MFMA clusters (2 desynced blocks/SIMD).
__global__ __launch_bounds__(256, 2) void flash_kernel(const char* __restrict__ q8,
                                                       const char* __restrict__ k8,
                                                       const char* __restrict__ v8,
                                                       short* __restrict__ Opart,
                                                       float* __restrict__ ml) {
    __shared__ __align__(16) char smem[68096];   // K dbuf 32K | V dbuf 32K | P 2.5K
    int bx = blockIdx.x;                 // 0..511
    int pb = bx & 7;                     // XCD-local (part,b)
    int part = pb >> 2, b = pb & 3;
    int q0 = (bx >> 3) * 64;
    int t = threadIdx.x, w = t >> 6, lane = t & 63;
    int l15 = lane & 15, l4 = lane >> 4;
    const float c2 = 0.06375873735f;     // (1/sqrt(512)) * log2(e)
    const float MARGIN = 7.2134752f;     // 5*log2(e); p <= 2^7.21 = 148 < 448

    // Q fp8 fragments: rows w*16 + l15, all 512 k (8 B per ks-step)
    long qf[16];
    {
        const char* qrow = q8 + ((size_t)b * SEQ + q0 + w * 16 + l15) * 512;
        #pragma unroll
        for (int ks = 0; ks < 16; ++ks)
            qf[ks] = *reinterpret_cast<const long*>(qrow + ks * 32 + l4 * 8);
    }

    floatx4 acc[32];
    #pragma unroll
    for (int i = 0; i < 32; ++i) acc[i] = (floatx4){0.f, 0.f, 0.f, 0.f};
    floatx4 lacc = (floatx4){0.f, 0.f, 0.f, 0.f};
    float mused[4] = {-1e30f, -1e30f, -1e30f, -1e30f};

    const long ones = 0x3838383838383838L;   // e4m3 1.0 x8

    const char* kbase = k8 + (size_t)b * SEQ * 512;
    const char* vbase = v8 + (size_t)b * 512 * SEQ;
    const int sb0 = part * 64;           // first 32-s block of this part

    const int ksw = l15 & 7;
    const int vsw = (l15 >> 1) & 3;
    // loop-invariant LDS read bases; per-iter offset = cur*16384 (+ immediates)
    const char* kA_E = smem + ((l15 * 64 + (l4 ^ ksw)) << 4);
    const char* kA_O = smem + ((l15 * 64 + ((4 + l4) ^ ksw)) << 4);
    const char* vA   = smem + 32768 + ((l15 * 4 + (l4 ^ vsw)) << 4);
    char* Ps = smem + 65536 + w * 640;

    // precomputed per-thread DMA source byte-offsets (swizzle folded in)
    int kSrc[4], vSrc[4];
    #pragma unroll
    for (int i = 0; i < 4; ++i) {
        int c = i * 256 + t;
        kSrc[i] = (((c & ~63) | ((c & 63) ^ ((c >> 6) & 7))) << 4);
        vSrc[i] = (((c & ~3)  | ((c & 3)  ^ ((c >> 3) & 3))) << 4);
    }
    const int ldsD = (t & ~63) << 4;   // wave-uniform: w*1024

    auto stage = [&](int sb, int buf) {
        const char* kt = kbase + (size_t)sb * 16384;
        const char* vt = vbase + (size_t)sb * 16384;
        char* Kd = smem + buf * 16384 + ldsD;
        char* Vd = smem + 32768 + buf * 16384 + ldsD;
        #pragma unroll
        for (int i = 0; i < 4; ++i) dma16(kt + kSrc[i], Kd + i * 4096);
        #pragma unroll
        for (int i = 0; i < 4; ++i) dma16(vt + vSrc[i], Vd + i * 4096);
    };

    stage(sb0, 0);
    __syncthreads();                                   // tile 0 ready

    for (int it = 0; it < 64; ++it) {
        int cur = it & 1;
        int coff = cur << 14;
        if (it + 1 < 64) stage(sb0 + it + 1, 1 - cur);

        // --- QK^T (fp8): one b128 per pair: low 8B = K row l15, high = l15+16
        floatx4 sa0 = (floatx4){0.f, 0.f, 0.f, 0.f};
        floatx4 sa1 = (floatx4){0.f, 0.f, 0.f, 0.f};
        __builtin_amdgcn_s_setprio(1);
        #pragma unroll
        for (int j = 0; j < 8; ++j) {
            longx2 kE = *reinterpret_cast<const longx2*>(kA_E + coff + j * 128);
            longx2 kO = *reinterpret_cast<const longx2*>(kA_O + coff + j * 128);
            sa0 = __builtin_amdgcn_mfma_f32_16x16x32_fp8_fp8(qf[2 * j],     kE[0], sa0, 0, 0, 0);
            sa1 = __builtin_amdgcn_mfma_f32_16x16x32_fp8_fp8(qf[2 * j],     kE[1], sa1, 0, 0, 0);
            sa0 = __builtin_amdgcn_mfma_f32_16x16x32_fp8_fp8(qf[2 * j + 1], kO[0], sa0, 0, 0, 0);
            sa1 = __builtin_amdgcn_mfma_f32_16x16x32_fp8_fp8(qf[2 * j + 1], kO[1], sa1, 0, 0, 0);
        }
        __builtin_amdgcn_s_setprio(0);

        // --- online softmax, base-2, lazy rescale
        float v0[4], v1[4], nm4[4];
        bool need = false;
        #pragma unroll
        for (int r = 0; r < 4; ++r) {
            v0[r] = sa0[r] * c2; v1[r] = sa1[r] * c2;
            nm4[r] = rowmax16(fmaxf(v0[r], v1[r]));
            need |= (nm4[r] > mused[r] + MARGIN);
        }
        if (__ballot(need)) {
            #pragma unroll
            for (int r = 0; r < 4; ++r) {
                float nm = fmaxf(mused[r], nm4[r]);
                float al = exp2f(mused[r] - nm);
                lacc[r] *= al;
                #pragma unroll
                for (int i = 0; i < 32; ++i) acc[i][r] *= al;
                mused[r] = nm;
            }
        }
        // P (fp8) write: interleaved col pairs (c, c+16) -> mem cols (2c, 2c+1).
        #pragma unroll
        for (int r = 0; r < 4; ++r) {
            int pk = __builtin_amdgcn_cvt_pk_fp8_f32(exp2f(v0[r] - mused[r]),
                                                     exp2f(v1[r] - mused[r]), 0, false);
            *reinterpret_cast<short*>(Ps + (l4 * 4 + r) * 40 + l15 * 2) = (short)pk;
        }

        // A-frag read via memcpy (may-alias pun -> ordered AFTER the short stores)
        long pf;
        __builtin_memcpy(&pf, (const char*)__builtin_assume_aligned(Ps + l15 * 40 + l4 * 8, 8), 8);
        __builtin_amdgcn_s_setprio(1);
        lacc = __builtin_amdgcn_mfma_f32_16x16x32_fp8_fp8(pf, ones, lacc, 0, 0, 0);
        // --- PV: one b128 per pair: low 8B = V row d, high 8B = V row d+16.
        #pragma unroll
        for (int g = 0; g < 16; ++g) {
            longx2 vv = *reinterpret_cast<const longx2*>(vA + coff + g * 1024);
            acc[2 * g]     = __builtin_amdgcn_mfma_f32_16x16x32_fp8_fp8(pf, vv[0], acc[2 * g],     0, 0, 0);
            acc[2 * g + 1] = __builtin_amdgcn_mfma_f32_16x16x32_fp8_fp8(pf, vv[1], acc[2 * g + 1], 0, 0, 0);
        }
        __builtin_amdgcn_s_setprio(0);

        __syncthreads();    // drains DMA(it+1) + all reads of buf[cur] done
    }

    short* obase = Opart + (((size_t)part * BATCH + b) * SEQ + q0 + w * 16) * 512;
    #pragma unroll
    for (int r = 0; r < 4; ++r) {
        #pragma unroll
        for (int tt = 0; tt < 32; ++tt)
            obase[(size_t)(l4 * 4 + r) * 512 + tt * 16 + l15] = bf16b(acc[tt][r]);
    }
    if (l15 == 0) {
        #pragma unroll
        for (int r = 0; r < 4; ++r) {
            size_t rowg = ((size_t)part * BATCH + b) * SEQ + q0 + w * 16 + l4 * 4 + r;
            ml[rowg * 2]     = mused[r];      // base-2 units
            ml[rowg * 2 + 1] = lacc[r];
        }
    }
}

extern "C" void kernel_launch(void* const* d_in, const int* in_sizes, int n_in,
                              void* d_out, int out_size, void* d_ws, size_t ws_size,
                              hipStream_t stream) {
    const float* x   = (const float*)d_in[0];
    const float* gsc = (const float*)d_in[1];
    const float* gbs = (const float*)d_in[2];
    const float* wq  = (const float*)d_in[3];
    const float* bq  = (const float*)d_in[4];
    const float* wk  = (const float*)d_in[5];
    const float* bk  = (const float*)d_in[6];
    const float* wv  = (const float*)d_in[7];
    const float* bv  = (const float*)d_in[8];
    const float* wo  = (const float*)d_in[9];
    const float* bo  = (const float*)d_in[10];
    float* out = (float*)d_out;

    char* ws = (char*)d_ws;
    const size_t MB = 1ull << 20;
    // [0,16)  xn bf16 (GEMM A input, dead after QKV GEMM)
    // [16,24) q8; [24,32) k8; [32,40) vT8 (fp8, from gemm_qkv epilogue)
    // [40,72) Opart bf16 (2 parts); [72,74) wT; [74,..) stats + ml
    short* xn    = (short*)ws;
    char*  q8    = (char*)(ws + 16 * MB);
    char*  k8    = (char*)(ws + 24 * MB);
    char*  vT8   = (char*)(ws + 32 * MB);
    short* Opart = (short*)(ws + 40 * MB);
    short* wT    = (short*)(ws + 72 * MB);
    float* stats = (float*)(ws + 74 * MB);
    float* ml    = (float*)(ws + 74 * MB + 65536);

    hipMemsetAsync(stats, 0, 256 * sizeof(float), stream);
    gn_partial_kernel<<<256, 256, 0, stream>>>(x, stats);
    gn_apply_kernel<<<8192, 256, 0, stream>>>(x, stats, gsc, gbs, xn);
    wtrans_kernel<<<dim3(16, 16, 4), dim3(32, 8), 0, stream>>>(wq, wk, wv, wo, wT);

    short* woT = wT + 786432;

    gemm_qkv_kernel<<<dim3(128, 12), 256, 0, stream>>>(xn, wT, bq, bk, bv, q8, k8, vT8);
    flash_kernel<<<512, 256, 0, stream>>>(q8, k8, vT8, Opart, ml);
    gemm_bt_kernel<<<dim3(128, 4), 256, 0, stream>>>(Opart, ml, woT, bo, out, x);
}